// Round 8
// baseline (316.741 us; speedup 1.0000x reference)
//
#include <hip/hip_runtime.h>
#include <hip/hip_bf16.h>
#include <math.h>

using bf16 = __hip_bfloat16;
typedef __attribute__((ext_vector_type(8))) __bf16 bf16x8;
typedef __attribute__((ext_vector_type(4))) float f32x4;

#define SBAR() asm volatile("s_barrier" ::: "memory")
#define WAITVM(n) asm volatile("s_waitcnt vmcnt(" #n ")" ::: "memory")
#define LGKMC(n) { asm volatile("s_waitcnt lgkmcnt(" #n ")" ::: "memory"); __builtin_amdgcn_sched_barrier(0); }
// inline-asm ds_read_b128: invisible to compiler alias tracking (no auto drains)
#define DSR(dst, a, o) asm volatile("ds_read_b128 %0, %1 offset:" o : "=v"(dst) : "v"(a))

static __device__ __forceinline__ void gload16(const bf16* g, bf16* l) {
  __builtin_amdgcn_global_load_lds((const __attribute__((address_space(1))) void*)g,
                                   (__attribute__((address_space(3))) void*)l, 16, 0, 0);
}

struct GP {
  const bf16* A[6]; const bf16* B[6]; char* C[6];
  const float* bias[6];
  int K[6], flags[6], ktOff[6];   // flags: 1=causal-skip 2=bias-row 4=f32out 8=ktrunc
};
struct CvtP { const float* s[5]; bf16* d[5]; int n4[5]; };

// ---------------------------------------------------------------------------
// fused f32 -> bf16 conversion for 5 tensors
// ---------------------------------------------------------------------------
__global__ __launch_bounds__(256) void cvt_f32_bf16(CvtP p) {
  const int y = blockIdx.y;
  const int i = blockIdx.x * 256 + threadIdx.x;
  if (i >= p.n4[y]) return;
  const float4 v = reinterpret_cast<const float4*>(p.s[y])[i];
  union { bf16 h[4]; short4 s4; } u;
  u.h[0] = __float2bfloat16(v.x);
  u.h[1] = __float2bfloat16(v.y);
  u.h[2] = __float2bfloat16(v.z);
  u.h[3] = __float2bfloat16(v.w);
  *reinterpret_cast<short4*>(p.d[y] + 4 * (size_t)i) = u.s4;
}

// ---------------------------------------------------------------------------
// 8-phase NT GEMM with REGISTER LOOKAHEAD: C = A[M,K]*B[N,K]^T.
// BM=BN=256, BK=64, 512 thr / 8 waves (2M x 4N), per-wave 128x64 (acc[8][4]).
// LDS: 2 dbuf x {A-k0, A-k1, B-k0, B-k1} halves (16KB each, 128KB total).
// Fragment sets: S1={A-k0 m0-3, B-k0}(8 reads) S2={A-k0 m4-7}(4)
//                S3={A-k1 m0-3, B-k1}(8)       S4={A-k1 m4-7}(4)
// Phase p: {ds_read set p+1 (into other reg buffer); stage 1 half of t+1;
//   [vmcnt(2) at P1/P3]; s_barrier; lgkmcnt(#just-issued) (waits only the
//   PREVIOUS phase's reads, which drained under last MFMA cluster);
//   setprio(1); 16 MFMA on set p; setprio(0)}.
// This decouples ds_read drain from MFMA issue: reads of phase p+1 drain
// under phase p's MFMAs -> LDS and matrix pipes overlap.
// vmcnt(2)@P1: h1(t),h3(t) landed (read at P2). vmcnt(2)@P3: h0,h2(t+1)
// landed (read at P4's S1(t+1) lookahead). Last tile: vmcnt(0)@P1.
// Reg WAR verified: each frag reg rewritten >=2 phases after last MFMA use.
// Swizzle: 16B slot = chunk ^ ((row>>1)&3) (measured 0 conflicts).
// ---------------------------------------------------------------------------
__global__ __launch_bounds__(512, 1) void gemm8p(GP P, int lda, int ldb, int ldc) {
  const int z = blockIdx.z;
  const int fl = P.flags[z];
  if ((fl & 1) && blockIdx.x > blockIdx.y) return;      // causal block skip
  const int by = (fl & 8) ? ((int)gridDim.y - 1 - (int)blockIdx.y) : (int)blockIdx.y;
  const int rowBase = by * 256;
  const int colBase = (int)blockIdx.x * 256;
  int kEnd = P.K[z];
  if (fl & 8) {
    const int lim = rowBase + 256 - P.ktOff[z];
    kEnd = kEnd < lim ? kEnd : lim;
    if (kEnd <= 0) return;                              // inert split-K block
  }
  const int NT = kEnd >> 6;                             // BK=64 tiles (>=4)

  const int tid  = threadIdx.x;
  const int lane = tid & 63;
  const int wid  = tid >> 6;
  const int wm = wid >> 2;          // 0..1 -> 128-row strip
  const int wn = wid & 3;           // 0..3 -> 64-col strip

  __shared__ alignas(16) bf16 ls[2][4][8192];  // [dbuf][A-k0,A-k1,B-k0,B-k1]

  f32x4 acc[8][4] = {};

  // staging: per half-tile 2 passes of 512thr x 16B; row = pass*128 + tid>>2
  const int r0  = tid >> 2;
  const int sw8 = ((tid & 3) ^ ((r0 >> 1) & 3)) * 8;    // pre-swizzled chunk
  const bf16* gA = P.A[z] + (size_t)(rowBase + r0) * lda + sw8;
  const bf16* gB = P.B[z] + (size_t)(colBase + r0) * ldb + sw8;

  // fragment read BYTE addresses (LDS): row*64B + swizzled-chunk*16B
  const uint lsbase = (uint)(size_t)(__attribute__((address_space(3))) void*)&ls[0][0][0];
  const int lr = lane >> 4, lc = lane & 15;
  uint aB[8], bB[4];
#pragma unroll
  for (int mi = 0; mi < 8; ++mi) {
    const int row = wm * 128 + mi * 16 + lc;
    aB[mi] = lsbase + (uint)(row * 64 + (lr ^ ((row >> 1) & 3)) * 16);
  }
#pragma unroll
  for (int ni = 0; ni < 4; ++ni) {
    const int row = wn * 64 + ni * 16 + lc;
    bB[ni] = lsbase + 32768u + (uint)(row * 64 + (lr ^ ((row >> 1) & 3)) * 16);
  }

  // stage half h of tile t: h 0=A-k0 1=A-k1 2=B-k0 3=B-k1
#define STG(t, h) { bf16* d = &ls[(t) & 1][h][0]; \
    if ((h) < 2) { const int ko = (t) * 64 + (h) * 32; \
      gload16(gA + ko, &d[tid * 8]); \
      gload16(gA + (size_t)128 * lda + ko, &d[4096 + tid * 8]); \
    } else { const int ko = (t) * 64 + ((h) - 2) * 32; \
      gload16(gB + ko, &d[tid * 8]); \
      gload16(gB + (size_t)128 * ldb + ko, &d[4096 + tid * 8]); } }

  bf16x8 aL[4], aH[4], b0[4], b1[4];   // persistent frag regs (lookahead)

  // prologue: tile 0 fully staged, drain, publish, preload S1(0)
  STG(0, 0); STG(0, 2); STG(0, 1); STG(0, 3);
  WAITVM(0);
  SBAR();
#pragma unroll
  for (int i = 0; i < 4; ++i) DSR(aL[i], aB[i], "0");
#pragma unroll
  for (int i = 0; i < 4; ++i) DSR(b0[i], bB[i], "0");

  for (int t = 0; t < NT; ++t) {
    const uint cur = (uint)(t & 1) << 16;
    const uint nxt = cur ^ (1u << 16);
    uint ao[8], bo[4];
#pragma unroll
    for (int i = 0; i < 8; ++i) ao[i] = aB[i] + cur;
#pragma unroll
    for (int i = 0; i < 4; ++i) bo[i] = bB[i] + cur;
    const bool more = (t + 1 < NT);

    // ---- P1: read S2(t) [4]; stage h0(t+1); vmcnt; MFMA S1 = aL x b0
#pragma unroll
    for (int i = 0; i < 4; ++i) DSR(aH[i], ao[4 + i], "0");
    if (more) { STG(t + 1, 0); WAITVM(2); } else { WAITVM(0); }
    SBAR();
    LGKMC(4);
    __builtin_amdgcn_s_setprio(1);
#pragma unroll
    for (int m = 0; m < 4; ++m)
#pragma unroll
      for (int n = 0; n < 4; ++n)
        acc[m][n] = __builtin_amdgcn_mfma_f32_16x16x32_bf16(aL[m], b0[n], acc[m][n], 0, 0, 0);
    __builtin_amdgcn_s_setprio(0);

    // ---- P2: read S3(t) [8]; stage h2(t+1); MFMA S2 = aH x b0
#pragma unroll
    for (int i = 0; i < 4; ++i) DSR(aL[i], ao[i], "16384");
#pragma unroll
    for (int i = 0; i < 4; ++i) DSR(b1[i], bo[i], "16384");
    if (more) STG(t + 1, 2);
    SBAR();
    LGKMC(8);
    __builtin_amdgcn_s_setprio(1);
#pragma unroll
    for (int m = 0; m < 4; ++m)
#pragma unroll
      for (int n = 0; n < 4; ++n)
        acc[4 + m][n] = __builtin_amdgcn_mfma_f32_16x16x32_bf16(aH[m], b0[n], acc[4 + m][n], 0, 0, 0);
    __builtin_amdgcn_s_setprio(0);

    // ---- P3: read S4(t) [4]; stage h1(t+1); vmcnt; MFMA S3 = aL x b1
#pragma unroll
    for (int i = 0; i < 4; ++i) DSR(aH[i], ao[4 + i], "16384");
    if (more) { STG(t + 1, 1); WAITVM(2); }
    SBAR();
    LGKMC(4);
    __builtin_amdgcn_s_setprio(1);
#pragma unroll
    for (int m = 0; m < 4; ++m)
#pragma unroll
      for (int n = 0; n < 4; ++n)
        acc[m][n] = __builtin_amdgcn_mfma_f32_16x16x32_bf16(aL[m], b1[n], acc[m][n], 0, 0, 0);
    __builtin_amdgcn_s_setprio(0);

    // ---- P4: read S1(t+1) [8] (lookahead, other dbuf); stage h3(t+1);
    //          MFMA S4 = aH x b1
    if (more) {
#pragma unroll
      for (int i = 0; i < 4; ++i) DSR(aL[i], aB[i] + nxt, "0");
#pragma unroll
      for (int i = 0; i < 4; ++i) DSR(b0[i], bB[i] + nxt, "0");
      STG(t + 1, 3);
      SBAR();
      LGKMC(8);
    } else {
      SBAR();
      LGKMC(0);
    }
    __builtin_amdgcn_s_setprio(1);
#pragma unroll
    for (int m = 0; m < 4; ++m)
#pragma unroll
      for (int n = 0; n < 4; ++n)
        acc[4 + m][n] = __builtin_amdgcn_mfma_f32_16x16x32_bf16(aH[m], b1[n], acc[4 + m][n], 0, 0, 0);
    __builtin_amdgcn_s_setprio(0);
  }
#undef STG

  const float* bias = P.bias[z];
  char* C = P.C[z];
#pragma unroll
  for (int m = 0; m < 8; ++m) {
    const int row0 = rowBase + wm * 128 + m * 16 + lr * 4;
#pragma unroll
    for (int n = 0; n < 4; ++n) {
      const int col = colBase + wn * 64 + n * 16 + lc;
      const float bcol = (bias && !(fl & 2)) ? bias[col] : 0.f;
#pragma unroll
      for (int j = 0; j < 4; ++j) {
        float v = acc[m][n][j] + bcol;
        if (fl & 2) v += bias[row0 + j];               // bias along rows (VT)
        const long idx = (long)(row0 + j) * ldc + col;
        if (fl & 4) reinterpret_cast<float*>(C)[idx] = v;
        else        reinterpret_cast<bf16*>(C)[idx] = __float2bfloat16(v);
      }
    }
  }
}

// ---------------------------------------------------------------------------
// RoPE on first 128 dims, in-place on bf16 [8192, 2048] (Q then K); pos=row%2048
// ---------------------------------------------------------------------------
__global__ __launch_bounds__(256) void rope_bf16(bf16* __restrict__ X) {
  const int idx = blockIdx.x * 256 + threadIdx.x;  // 8192*64 pairs
  const int row = idx >> 6;
  const int i   = idx & 63;
  const int t   = row & 2047;
  const float ang = (float)t * exp2f((float)i * -0.20762050593046f);
  float sn, cs;
  sincosf(ang, &sn, &cs);
  bf16* p = X + ((long)row << 11) + 2 * i;
  const float x1 = __bfloat162float(p[0]);
  const float x2 = __bfloat162float(p[1]);
  p[0] = __float2bfloat16(x1 * cs - x2 * sn);
  p[1] = __float2bfloat16(x2 * cs + x1 * sn);
}

// ---------------------------------------------------------------------------
// Causal row softmax over split-K partials; writes bf16 A row (stride 4096,
// zeros above diagonal), scale 1/sqrt(128), x2 factor.
// ---------------------------------------------------------------------------
__global__ __launch_bounds__(256) void softmax_causal(
    const float* __restrict__ S0, const float* __restrict__ S1,
    const float* __restrict__ S2, const float* __restrict__ S3,
    bf16* __restrict__ A0, bf16* __restrict__ A1) {
  const int t = blockIdx.x;
  const int b = blockIdx.y;
  const float* ra = (b ? S2 : S0) + (long)t * 2048;
  const float* rb = (b ? S3 : S1) + (long)t * 2048;
  bf16* orow = (b ? A1 : A0) + (long)t * 4096;
  const int L = t + 1;
  __shared__ float e[2048];
  __shared__ float red[4];
  const float scale = 0.0883883476483184f;  // 1/sqrt(128)
  const int lane = threadIdx.x & 63, wd = threadIdx.x >> 6;

  float mx = -INFINITY;
  for (int s = threadIdx.x; s < L; s += 256) {
    const float v = (ra[s] + rb[s]) * scale;
    e[s] = v;
    mx = fmaxf(mx, v);
  }
#pragma unroll
  for (int off = 1; off < 64; off <<= 1) mx = fmaxf(mx, __shfl_xor(mx, off));
  if (lane == 0) red[wd] = mx;
  __syncthreads();
  mx = fmaxf(fmaxf(red[0], red[1]), fmaxf(red[2], red[3]));
  __syncthreads();

  float sum = 0.f;
  for (int s = threadIdx.x; s < L; s += 256) {
    const float v = expf(e[s] - mx);
    e[s] = v;
    sum += v;
  }
#pragma unroll
  for (int off = 1; off < 64; off <<= 1) sum += __shfl_xor(sum, off);
  if (lane == 0) red[wd] = sum;
  __syncthreads();
  sum = red[0] + red[1] + red[2] + red[3];
  const float f = 2.f / sum;
  for (int s = threadIdx.x; s < 2048; s += 256) {
    const float v = (s < L) ? e[s] * f : 0.f;
    orow[s] = __float2bfloat16(v);
  }
}

// ---------------------------------------------------------------------------
// PV reduce: O = bf16(P0 + (row>=1024 ? P1 : 0));  P0 split per batch.
// ---------------------------------------------------------------------------
__global__ __launch_bounds__(256) void pv_reduce(
    const float* __restrict__ p0a, const float* __restrict__ p0b,
    const float* __restrict__ p1, bf16* __restrict__ O) {
  const long i4 = (long)blockIdx.x * 256 + threadIdx.x;  // [0, 2*2048*2048/4)
  const long g = i4 * 4;
  const int b = (int)(g >> 22);
  const long rem = g & ((1L << 22) - 1);
  const int r = (int)(rem >> 11);
  const float* p0 = b ? p0b : p0a;
  float4 v = *reinterpret_cast<const float4*>(p0 + rem);
  if (r >= 1024) {
    const float4 w = *reinterpret_cast<const float4*>(
        p1 + (long)b * (1024 * 2048) + (rem - (1L << 21)));
    v.x += w.x; v.y += w.y; v.z += w.z; v.w += w.w;
  }
  union { bf16 h[4]; short4 s; } u;
  u.h[0] = __float2bfloat16(v.x);
  u.h[1] = __float2bfloat16(v.y);
  u.h[2] = __float2bfloat16(v.z);
  u.h[3] = __float2bfloat16(v.w);
  *reinterpret_cast<short4*>(O + g) = u.s;
}

// ---------------------------------------------------------------------------
extern "C" void kernel_launch(void* const* d_in, const int* in_sizes, int n_in,
                              void* d_out, int out_size, void* d_ws, size_t ws_size,
                              hipStream_t stream) {
  (void)in_sizes; (void)n_in; (void)out_size; (void)ws_size;
  const float* lat = (const float*)d_in[0];
  const float* Wq  = (const float*)d_in[1];
  const float* bq  = (const float*)d_in[2];
  const float* Wk  = (const float*)d_in[3];
  const float* bk  = (const float*)d_in[4];
  const float* Wv  = (const float*)d_in[5];
  const float* bv  = (const float*)d_in[6];
  const float* Wfc = (const float*)d_in[7];
  const float* bfc = (const float*)d_in[8];
  float* out = (float*)d_out;

  constexpr long T = 2048, D = 2048, MT = 4096;    // B=2
  constexpr long TTB = T * T * 4;                  // 16.78 MB per f32 score buf
  char* w = (char*)d_ws;
  bf16* latb = (bf16*)w;  w += MT * D * 2;         // later overlaid by O
  bf16* wqb  = (bf16*)w;  w += D * D * 2;
  bf16* wkb  = (bf16*)w;  w += D * D * 2;
  bf16* wvb  = (bf16*)w;  w += D * D * 2;
  bf16* wfb  = (bf16*)w;  w += D * D * 2;
  bf16* Qb   = (bf16*)w;  w += MT * D * 2;         // Q,K contiguous (rope)
  bf16* Kb   = (bf16*)w;  w += MT * D * 2;
  bf16* VTb  = (bf16*)w;  w += MT * D * 2;
  float* S0  = (float*)w; w += TTB;                // b0 khalf0 partial
  float* S1  = (float*)w; w += TTB;                // b0 khalf1 partial
  float* P1w = (float*)w; w += TTB;                // PV khalf1 partial
  float* S2  = (float*)d_out;                      // b1 khalf0 (d_out lower)
  float* S3  = (float*)((char*)d_out + TTB);       // b1 khalf1 (d_out upper)
  bf16* A0   = (bf16*)S0;                          // A overlays (stride 4096)
  bf16* A1   = (bf16*)S3;
  float* P0a = S1;                                 // PV khalf0 partial, batch0
  float* P0b = S2;                                 // PV khalf0 partial, batch1
  bf16* Ob   = latb;                               // O overlays latb

  // 1) convert to bf16
  CvtP cp;
  cp.s[0] = lat; cp.d[0] = latb; cp.n4[0] = (int)(MT * D / 4);
  cp.s[1] = Wq;  cp.d[1] = wqb;  cp.n4[1] = (int)(D * D / 4);
  cp.s[2] = Wk;  cp.d[2] = wkb;  cp.n4[2] = (int)(D * D / 4);
  cp.s[3] = Wv;  cp.d[3] = wvb;  cp.n4[3] = (int)(D * D / 4);
  cp.s[4] = Wfc; cp.d[4] = wfb;  cp.n4[4] = (int)(D * D / 4);
  cvt_f32_bf16<<<dim3(8192, 5), 256, 0, stream>>>(cp);

  // 2) Q/K projections (+bias col)
  {
    GP P = {};
    P.A[0] = latb; P.B[0] = wqb; P.C[0] = (char*)Qb; P.bias[0] = bq; P.K[0] = 2048;
    P.A[1] = latb; P.B[1] = wkb; P.C[1] = (char*)Kb; P.bias[1] = bk; P.K[1] = 2048;
    gemm8p<<<dim3(8, 16, 2), 512, 0, stream>>>(P, 2048, 2048, 2048);
  }

  // 3) RoPE on Q and K (contiguous 8192 rows)
  rope_bf16<<<2048, 256, 0, stream>>>(Qb);

  // 4) VT-projection (z0,1: VT = Wv·lat^T + bv[row]) merged with causal
  //    split-K scores (z2..5)
  {
    GP P = {};
    for (int b = 0; b < 2; ++b) {
      P.A[b] = wvb; P.B[b] = latb + (long)b * T * D;
      P.C[b] = (char*)(VTb + (long)b * T * D);
      P.bias[b] = bv; P.K[b] = 2048; P.flags[b] = 2;   // bias-row, bf16 out
    }
    char* sc[4] = {(char*)S0, (char*)S1, (char*)S2, (char*)S3};
    for (int zz = 0; zz < 4; ++zz) {
      const int b = zz >> 1, kh = zz & 1;
      P.A[2 + zz] = Qb + (long)b * T * D + kh * 1024;
      P.B[2 + zz] = Kb + (long)b * T * D + kh * 1024;
      P.C[2 + zz] = sc[zz];
      P.K[2 + zz] = 1024; P.flags[2 + zz] = 1 | 4;     // causal, f32 out
    }
    gemm8p<<<dim3(8, 8, 6), 512, 0, stream>>>(P, 2048, 2048, 2048);
  }

  // 5) softmax rows (sum two k-half partials) -> bf16 A (stride 4096)
  softmax_causal<<<dim3(2048, 2), 256, 0, stream>>>(S0, S1, S2, S3, A0, A1);

  // 6) PV split-K: z = batch*2 + khalf; kEnd = min(1024, rowBase+256-kOff)
  {
    GP P = {};
    for (int z = 0; z < 4; ++z) {
      const int b = z >> 1, kh = z & 1;
      P.A[z] = (b ? A1 : A0) + kh * 1024;
      P.B[z] = VTb + (long)b * T * D + kh * 1024;
      P.C[z] = kh ? ((char*)P1w + (long)b * 1024 * 2048 * 4 - (long)1024 * 2048 * 4)
                  : (char*)(b ? P0b : P0a);
      P.K[z] = 1024; P.flags[z] = 8 | 4; P.ktOff[z] = kh * 1024;
    }
    gemm8p<<<dim3(8, 8, 4), 512, 0, stream>>>(P, 4096, 2048, 2048);
  }

  // 7) O = bf16(P0 + P1), into latb region
  pv_reduce<<<8192, 256, 0, stream>>>(P0a, P0b, P1w, Ob);

  // 8) out = O Wfc^T + bfc, unsplit (K=2048), f32 straight to d_out
  {
    GP P = {};
    P.A[0] = Ob; P.B[0] = wfb; P.C[0] = (char*)out;
    P.bias[0] = bfc; P.K[0] = 2048; P.flags[0] = 4;    // f32 out, bias col
    gemm8p<<<dim3(8, 16, 1), 512, 0, stream>>>(P, 2048, 2048, 2048);
  }
}

// Round 9
// 310.966 us; speedup vs baseline: 1.0186x; 1.0186x over previous
//
#include <hip/hip_runtime.h>
#include <hip/hip_bf16.h>
#include <math.h>

using bf16 = __hip_bfloat16;
typedef __attribute__((ext_vector_type(8))) __bf16 bf16x8;
typedef __attribute__((ext_vector_type(4))) float f32x4;

#define SBAR() asm volatile("s_barrier" ::: "memory")
#define WAITVM(n) asm volatile("s_waitcnt vmcnt(" #n ")" ::: "memory")
#define LGKM0() { asm volatile("s_waitcnt lgkmcnt(0)" ::: "memory"); __builtin_amdgcn_sched_barrier(0); }
#define DSR(dst, a) asm volatile("ds_read_b128 %0, %1" : "=v"(dst) : "v"(a))

static __device__ __forceinline__ void gload16(const bf16* g, bf16* l) {
  __builtin_amdgcn_global_load_lds((const __attribute__((address_space(1))) void*)g,
                                   (__attribute__((address_space(3))) void*)l, 16, 0, 0);
}

struct GP {
  const bf16* A[6]; const bf16* B[6]; char* C[6];
  const float* bias[6];
  int K[6], flags[6], ktOff[6];   // flags: 1=causal-skip 2=bias-row 4=f32out 8=ktrunc
};
struct CvtP { const float* s[5]; bf16* d[5]; int n4[5]; };

// ---------------------------------------------------------------------------
// fused f32 -> bf16 conversion for 5 tensors
// ---------------------------------------------------------------------------
__global__ __launch_bounds__(256) void cvt_f32_bf16(CvtP p) {
  const int y = blockIdx.y;
  const int i = blockIdx.x * 256 + threadIdx.x;
  if (i >= p.n4[y]) return;
  const float4 v = reinterpret_cast<const float4*>(p.s[y])[i];
  union { bf16 h[4]; short4 s4; } u;
  u.h[0] = __float2bfloat16(v.x);
  u.h[1] = __float2bfloat16(v.y);
  u.h[2] = __float2bfloat16(v.z);
  u.h[3] = __float2bfloat16(v.w);
  *reinterpret_cast<short4*>(p.d[y] + 4 * (size_t)i) = u.s4;
}

// ---------------------------------------------------------------------------
// m201-faithful 8-phase NT GEMM: C = A[M,K]*B[N,K]^T. BM=BN=256, BK=64,
// 512 thr / 8 waves (2M x 4N), per-wave 128x64 (acc[8][4]).
// LDS: 2 dbuf x {Ah0(rows0-127), Ah1, Bh0, Bh1} x 128x64 bf16 (16KB) = 128KB.
// Per tile u, 4 phases (2 barriers each, rolling stage, counted vmcnt):
//  u.1: read A m0-3 (8) + B n0-1 (4); stage Ah1(u+1); lgkm(8); BAR; lgkm(0);
//       16 MFMA m0-3 x n0-1; BAR.
//  u.2: read B n2-3 (4); BAR; lgkm(0); 16 MFMA m0-3 x n2-3; BAR.
//  u.3: read A m4-7 (8); stage Bh0(u+2); BAR; lgkm(0); 16 MFMA m4-7 x n2-3; BAR.
//  u.4: stage Bh1(u+2), Ah0(u+2); vmcnt(6) [or 0 at tail]; BAR;
//       16 MFMA m4-7 x n0-1 (b01 regs held since u.1); BAR.
// vmcnt(6) FIFO accounting (steady state, 14 outstanding): drains exactly
// tile u+1's 8 loads, leaves the 6 newest (tile u+2's 3 halves) in flight
// -> issue->wait distance 4-7 phases, HBM latency fully hidden.
// WAR: each stage targets a half whose last reader phase completed one full
// barrier-pair earlier (Ah1(u+1) region free at (u-1).4; Bh(u+2) free at
// u.3; Ah0(u+2) free at u.4).
// Swizzle (128B rows, 8x16B chunks): slot = chunk ^ (row&7) -> uniform
// 8 lanes per 4-bank group on ds_read_b128 (conflict-free); gload_lds dest
// linear, source pre-swizzled with the same involution.
// ---------------------------------------------------------------------------
__global__ __launch_bounds__(512, 2) void gemm8p(GP P, int lda, int ldb, int ldc) {
  const int z = blockIdx.z;
  const int fl = P.flags[z];
  if ((fl & 1) && blockIdx.x > blockIdx.y) return;      // causal block skip
  const int by = (fl & 8) ? ((int)gridDim.y - 1 - (int)blockIdx.y) : (int)blockIdx.y;
  const int rowBase = by * 256;
  const int colBase = (int)blockIdx.x * 256;
  int kEnd = P.K[z];
  if (fl & 8) {
    const int lim = rowBase + 256 - P.ktOff[z];
    kEnd = kEnd < lim ? kEnd : lim;
    if (kEnd <= 0) return;                              // inert split-K block
  }
  const int NT = kEnd >> 6;                             // BK=64 tiles (>=4)

  const int tid  = threadIdx.x;
  const int lane = tid & 63;
  const int wid  = tid >> 6;
  const int wm = wid >> 2;          // 0..1 -> 128-row strip
  const int wn = wid & 3;           // 0..3 -> 64-col strip

  __shared__ alignas(16) bf16 ls[2][4][8192];  // [dbuf][Ah0,Ah1,Bh0,Bh1]

  f32x4 acc[8][4] = {};

  // staging: half = 128 rows x 64 k; 2 gload passes (rows 0-63 / 64-127).
  // per-thread: row rA = tid>>3, chunk slot = tid&7, source chunk pre-swizzled.
  const int rA  = tid >> 3;                             // 0..63
  const int cs8 = ((tid & 7) ^ (rA & 7)) * 8;           // src k-offset (elems)
  const bf16* gAp = P.A[z] + (size_t)(rowBase + rA) * lda + cs8;
  const bf16* gBp = P.B[z] + (size_t)(colBase + rA) * ldb + cs8;

  // fragment read byte addresses (dbuf0, kk0); kk1 = addr ^ 64
  const uint lsbase = (uint)(size_t)(__attribute__((address_space(3))) void*)&ls[0][0][0];
  const int lr = lane >> 4, lc = lane & 15;
  uint aA[8], aB_[4];
#pragma unroll
  for (int mi = 0; mi < 8; ++mi) {
    const int r = mi * 16 + lc;                         // row in half (wave wm)
    aA[mi] = lsbase + (uint)wm * 16384u + (uint)(r * 128 + ((lr ^ (r & 7)) << 4));
  }
#pragma unroll
  for (int ni = 0; ni < 4; ++ni) {
    const int rg = wn * 64 + ni * 16 + lc;              // B row 0..255
    const int r = rg & 127;
    aB_[ni] = lsbase + (2u + (uint)(wn >> 1)) * 16384u + (uint)(r * 128 + ((lr ^ (r & 7)) << 4));
  }

  // stage half h of tile t: h 0=Ah0 1=Ah1 2=Bh0 3=Bh1
#define STGH(t, h) { bf16* d = &ls[(t) & 1][h][0]; \
    if ((h) < 2) { const bf16* s = gAp + (size_t)((h) * 128) * lda + (t) * 64; \
      gload16(s, d + tid * 8); gload16(s + (size_t)64 * lda, d + 4096 + tid * 8); \
    } else { const bf16* s = gBp + (size_t)(((h) - 2) * 128) * ldb + (t) * 64; \
      gload16(s, d + tid * 8); gload16(s + (size_t)64 * ldb, d + 4096 + tid * 8); } }

  // prologue: tile0 full (8 loads) + tile1 {Bh0,Bh1,Ah0} (6 loads);
  // Ah1(1) is staged at 0.1 per the rolling schedule.
  STGH(0, 0); STGH(0, 1); STGH(0, 2); STGH(0, 3);
  STGH(1, 2); STGH(1, 3); STGH(1, 0);
  WAITVM(6);                     // tile0 landed; tile1's 6 in flight
  SBAR();

  bf16x8 aLo0[4], aLo1[4], aHi0[4], aHi1[4];
  bf16x8 b010[2], b011[2], b230[2], b231[2];

  for (int u = 0; u < NT; ++u) {
    const uint dsel = (uint)(u & 1) << 16;
    const bool s1 = (u + 1 < NT), s2 = (u + 2 < NT);

    // ---- P1: read A m0-3 (8) + B n0-1 (4); stage Ah1(u+1)
#pragma unroll
    for (int mi = 0; mi < 4; ++mi) {
      const uint a = aA[mi] + dsel, a1 = a ^ 64u;
      DSR(aLo0[mi], a); DSR(aLo1[mi], a1);
    }
#pragma unroll
    for (int ni = 0; ni < 2; ++ni) {
      const uint b = aB_[ni] + dsel, b1 = b ^ 64u;
      DSR(b010[ni], b); DSR(b011[ni], b1);
    }
    if (s1) STGH(u + 1, 1);
    asm volatile("s_waitcnt lgkmcnt(8)" ::: "memory");
    SBAR();
    LGKM0();
    __builtin_amdgcn_s_setprio(1);
#pragma unroll
    for (int m = 0; m < 4; ++m)
#pragma unroll
      for (int n = 0; n < 2; ++n) {
        acc[m][n] = __builtin_amdgcn_mfma_f32_16x16x32_bf16(aLo0[m], b010[n], acc[m][n], 0, 0, 0);
        acc[m][n] = __builtin_amdgcn_mfma_f32_16x16x32_bf16(aLo1[m], b011[n], acc[m][n], 0, 0, 0);
      }
    __builtin_amdgcn_s_setprio(0);
    SBAR();

    // ---- P2: read B n2-3 (4)
#pragma unroll
    for (int ni = 0; ni < 2; ++ni) {
      const uint b = aB_[2 + ni] + dsel, b1 = b ^ 64u;
      DSR(b230[ni], b); DSR(b231[ni], b1);
    }
    SBAR();
    LGKM0();
    __builtin_amdgcn_s_setprio(1);
#pragma unroll
    for (int m = 0; m < 4; ++m)
#pragma unroll
      for (int n = 0; n < 2; ++n) {
        acc[m][2 + n] = __builtin_amdgcn_mfma_f32_16x16x32_bf16(aLo0[m], b230[n], acc[m][2 + n], 0, 0, 0);
        acc[m][2 + n] = __builtin_amdgcn_mfma_f32_16x16x32_bf16(aLo1[m], b231[n], acc[m][2 + n], 0, 0, 0);
      }
    __builtin_amdgcn_s_setprio(0);
    SBAR();

    // ---- P3: read A m4-7 (8); stage Bh0(u+2)
#pragma unroll
    for (int mi = 0; mi < 4; ++mi) {
      const uint a = aA[4 + mi] + dsel, a1 = a ^ 64u;
      DSR(aHi0[mi], a); DSR(aHi1[mi], a1);
    }
    if (s2) STGH(u + 2, 2);
    SBAR();
    LGKM0();
    __builtin_amdgcn_s_setprio(1);
#pragma unroll
    for (int m = 0; m < 4; ++m)
#pragma unroll
      for (int n = 0; n < 2; ++n) {
        acc[4 + m][2 + n] = __builtin_amdgcn_mfma_f32_16x16x32_bf16(aHi0[m], b230[n], acc[4 + m][2 + n], 0, 0, 0);
        acc[4 + m][2 + n] = __builtin_amdgcn_mfma_f32_16x16x32_bf16(aHi1[m], b231[n], acc[4 + m][2 + n], 0, 0, 0);
      }
    __builtin_amdgcn_s_setprio(0);
    SBAR();

    // ---- P4: stage Bh1(u+2), Ah0(u+2); vmcnt(6); MFMA m4-7 x n0-1 (no reads)
    if (s2) { STGH(u + 2, 3); STGH(u + 2, 0); WAITVM(6); } else { WAITVM(0); }
    SBAR();
    __builtin_amdgcn_s_setprio(1);
#pragma unroll
    for (int m = 0; m < 4; ++m)
#pragma unroll
      for (int n = 0; n < 2; ++n) {
        acc[4 + m][n] = __builtin_amdgcn_mfma_f32_16x16x32_bf16(aHi0[m], b010[n], acc[4 + m][n], 0, 0, 0);
        acc[4 + m][n] = __builtin_amdgcn_mfma_f32_16x16x32_bf16(aHi1[m], b011[n], acc[4 + m][n], 0, 0, 0);
      }
    __builtin_amdgcn_s_setprio(0);
    SBAR();
  }
#undef STGH

  const float* bias = P.bias[z];
  char* C = P.C[z];
#pragma unroll
  for (int m = 0; m < 8; ++m) {
    const int row0 = rowBase + wm * 128 + m * 16 + lr * 4;
#pragma unroll
    for (int n = 0; n < 4; ++n) {
      const int col = colBase + wn * 64 + n * 16 + lc;
      const float bcol = (bias && !(fl & 2)) ? bias[col] : 0.f;
#pragma unroll
      for (int j = 0; j < 4; ++j) {
        float v = acc[m][n][j] + bcol;
        if (fl & 2) v += bias[row0 + j];               // bias along rows (VT)
        const long idx = (long)(row0 + j) * ldc + col;
        if (fl & 4) reinterpret_cast<float*>(C)[idx] = v;
        else        reinterpret_cast<bf16*>(C)[idx] = __float2bfloat16(v);
      }
    }
  }
}

// ---------------------------------------------------------------------------
// RoPE on first 128 dims, in-place on bf16 [8192, 2048] (Q then K); pos=row%2048
// ---------------------------------------------------------------------------
__global__ __launch_bounds__(256) void rope_bf16(bf16* __restrict__ X) {
  const int idx = blockIdx.x * 256 + threadIdx.x;  // 8192*64 pairs
  const int row = idx >> 6;
  const int i   = idx & 63;
  const int t   = row & 2047;
  const float ang = (float)t * exp2f((float)i * -0.20762050593046f);
  float sn, cs;
  sincosf(ang, &sn, &cs);
  bf16* p = X + ((long)row << 11) + 2 * i;
  const float x1 = __bfloat162float(p[0]);
  const float x2 = __bfloat162float(p[1]);
  p[0] = __float2bfloat16(x1 * cs - x2 * sn);
  p[1] = __float2bfloat16(x2 * cs + x1 * sn);
}

// ---------------------------------------------------------------------------
// Causal row softmax over split-K partials; writes bf16 A row (stride 4096,
// zeros above diagonal), scale 1/sqrt(128), x2 factor.
// ---------------------------------------------------------------------------
__global__ __launch_bounds__(256) void softmax_causal(
    const float* __restrict__ S0, const float* __restrict__ S1,
    const float* __restrict__ S2, const float* __restrict__ S3,
    bf16* __restrict__ A0, bf16* __restrict__ A1) {
  const int t = blockIdx.x;
  const int b = blockIdx.y;
  const float* ra = (b ? S2 : S0) + (long)t * 2048;
  const float* rb = (b ? S3 : S1) + (long)t * 2048;
  bf16* orow = (b ? A1 : A0) + (long)t * 4096;
  const int L = t + 1;
  __shared__ float e[2048];
  __shared__ float red[4];
  const float scale = 0.0883883476483184f;  // 1/sqrt(128)
  const int lane = threadIdx.x & 63, wd = threadIdx.x >> 6;

  float mx = -INFINITY;
  for (int s = threadIdx.x; s < L; s += 256) {
    const float v = (ra[s] + rb[s]) * scale;
    e[s] = v;
    mx = fmaxf(mx, v);
  }
#pragma unroll
  for (int off = 1; off < 64; off <<= 1) mx = fmaxf(mx, __shfl_xor(mx, off));
  if (lane == 0) red[wd] = mx;
  __syncthreads();
  mx = fmaxf(fmaxf(red[0], red[1]), fmaxf(red[2], red[3]));
  __syncthreads();

  float sum = 0.f;
  for (int s = threadIdx.x; s < L; s += 256) {
    const float v = expf(e[s] - mx);
    e[s] = v;
    sum += v;
  }
#pragma unroll
  for (int off = 1; off < 64; off <<= 1) sum += __shfl_xor(sum, off);
  if (lane == 0) red[wd] = sum;
  __syncthreads();
  sum = red[0] + red[1] + red[2] + red[3];
  const float f = 2.f / sum;
  for (int s = threadIdx.x; s < 2048; s += 256) {
    const float v = (s < L) ? e[s] * f : 0.f;
    orow[s] = __float2bfloat16(v);
  }
}

// ---------------------------------------------------------------------------
// PV reduce: O = bf16(P0 + (row>=1024 ? P1 : 0));  P0 split per batch.
// ---------------------------------------------------------------------------
__global__ __launch_bounds__(256) void pv_reduce(
    const float* __restrict__ p0a, const float* __restrict__ p0b,
    const float* __restrict__ p1, bf16* __restrict__ O) {
  const long i4 = (long)blockIdx.x * 256 + threadIdx.x;  // [0, 2*2048*2048/4)
  const long g = i4 * 4;
  const int b = (int)(g >> 22);
  const long rem = g & ((1L << 22) - 1);
  const int r = (int)(rem >> 11);
  const float* p0 = b ? p0b : p0a;
  float4 v = *reinterpret_cast<const float4*>(p0 + rem);
  if (r >= 1024) {
    const float4 w = *reinterpret_cast<const float4*>(
        p1 + (long)b * (1024 * 2048) + (rem - (1L << 21)));
    v.x += w.x; v.y += w.y; v.z += w.z; v.w += w.w;
  }
  union { bf16 h[4]; short4 s; } u;
  u.h[0] = __float2bfloat16(v.x);
  u.h[1] = __float2bfloat16(v.y);
  u.h[2] = __float2bfloat16(v.z);
  u.h[3] = __float2bfloat16(v.w);
  *reinterpret_cast<short4*>(O + g) = u.s;
}

// ---------------------------------------------------------------------------
extern "C" void kernel_launch(void* const* d_in, const int* in_sizes, int n_in,
                              void* d_out, int out_size, void* d_ws, size_t ws_size,
                              hipStream_t stream) {
  (void)in_sizes; (void)n_in; (void)out_size; (void)ws_size;
  const float* lat = (const float*)d_in[0];
  const float* Wq  = (const float*)d_in[1];
  const float* bq  = (const float*)d_in[2];
  const float* Wk  = (const float*)d_in[3];
  const float* bk  = (const float*)d_in[4];
  const float* Wv  = (const float*)d_in[5];
  const float* bv  = (const float*)d_in[6];
  const float* Wfc = (const float*)d_in[7];
  const float* bfc = (const float*)d_in[8];
  float* out = (float*)d_out;

  constexpr long T = 2048, D = 2048, MT = 4096;    // B=2
  constexpr long TTB = T * T * 4;                  // 16.78 MB per f32 score buf
  char* w = (char*)d_ws;
  bf16* latb = (bf16*)w;  w += MT * D * 2;         // later overlaid by O
  bf16* wqb  = (bf16*)w;  w += D * D * 2;
  bf16* wkb  = (bf16*)w;  w += D * D * 2;
  bf16* wvb  = (bf16*)w;  w += D * D * 2;
  bf16* wfb  = (bf16*)w;  w += D * D * 2;
  bf16* Qb   = (bf16*)w;  w += MT * D * 2;         // Q,K contiguous (rope)
  bf16* Kb   = (bf16*)w;  w += MT * D * 2;
  bf16* VTb  = (bf16*)w;  w += MT * D * 2;
  float* S0  = (float*)w; w += TTB;                // b0 khalf0 partial
  float* S1  = (float*)w; w += TTB;                // b0 khalf1 partial
  float* P1w = (float*)w; w += TTB;                // PV khalf1 partial
  float* S2  = (float*)d_out;                      // b1 khalf0 (d_out lower)
  float* S3  = (float*)((char*)d_out + TTB);       // b1 khalf1 (d_out upper)
  bf16* A0   = (bf16*)S0;                          // A overlays (stride 4096)
  bf16* A1   = (bf16*)S3;
  float* P0a = S1;                                 // PV khalf0 partial, batch0
  float* P0b = S2;                                 // PV khalf0 partial, batch1
  bf16* Ob   = latb;                               // O overlays latb

  // 1) convert to bf16
  CvtP cp;
  cp.s[0] = lat; cp.d[0] = latb; cp.n4[0] = (int)(MT * D / 4);
  cp.s[1] = Wq;  cp.d[1] = wqb;  cp.n4[1] = (int)(D * D / 4);
  cp.s[2] = Wk;  cp.d[2] = wkb;  cp.n4[2] = (int)(D * D / 4);
  cp.s[3] = Wv;  cp.d[3] = wvb;  cp.n4[3] = (int)(D * D / 4);
  cp.s[4] = Wfc; cp.d[4] = wfb;  cp.n4[4] = (int)(D * D / 4);
  cvt_f32_bf16<<<dim3(8192, 5), 256, 0, stream>>>(cp);

  // 2) Q/K projections (+bias col)
  {
    GP P = {};
    P.A[0] = latb; P.B[0] = wqb; P.C[0] = (char*)Qb; P.bias[0] = bq; P.K[0] = 2048;
    P.A[1] = latb; P.B[1] = wkb; P.C[1] = (char*)Kb; P.bias[1] = bk; P.K[1] = 2048;
    gemm8p<<<dim3(8, 16, 2), 512, 0, stream>>>(P, 2048, 2048, 2048);
  }

  // 3) RoPE on Q and K (contiguous 8192 rows)
  rope_bf16<<<2048, 256, 0, stream>>>(Qb);

  // 4) VT-projection (z0,1: VT = Wv·lat^T + bv[row]) merged with causal
  //    split-K scores (z2..5)
  {
    GP P = {};
    for (int b = 0; b < 2; ++b) {
      P.A[b] = wvb; P.B[b] = latb + (long)b * T * D;
      P.C[b] = (char*)(VTb + (long)b * T * D);
      P.bias[b] = bv; P.K[b] = 2048; P.flags[b] = 2;   // bias-row, bf16 out
    }
    char* sc[4] = {(char*)S0, (char*)S1, (char*)S2, (char*)S3};
    for (int zz = 0; zz < 4; ++zz) {
      const int b = zz >> 1, kh = zz & 1;
      P.A[2 + zz] = Qb + (long)b * T * D + kh * 1024;
      P.B[2 + zz] = Kb + (long)b * T * D + kh * 1024;
      P.C[2 + zz] = sc[zz];
      P.K[2 + zz] = 1024; P.flags[2 + zz] = 1 | 4;     // causal, f32 out
    }
    gemm8p<<<dim3(8, 8, 6), 512, 0, stream>>>(P, 2048, 2048, 2048);
  }

  // 5) softmax rows (sum two k-half partials) -> bf16 A (stride 4096)
  softmax_causal<<<dim3(2048, 2), 256, 0, stream>>>(S0, S1, S2, S3, A0, A1);

  // 6) PV split-K: z = batch*2 + khalf; kEnd = min(1024, rowBase+256-kOff)
  {
    GP P = {};
    for (int z = 0; z < 4; ++z) {
      const int b = z >> 1, kh = z & 1;
      P.A[z] = (b ? A1 : A0) + kh * 1024;
      P.B[z] = VTb + (long)b * T * D + kh * 1024;
      P.C[z] = kh ? ((char*)P1w + (long)b * 1024 * 2048 * 4 - (long)1024 * 2048 * 4)
                  : (char*)(b ? P0b : P0a);
      P.K[z] = 1024; P.flags[z] = 8 | 4; P.ktOff[z] = kh * 1024;
    }
    gemm8p<<<dim3(8, 8, 4), 512, 0, stream>>>(P, 4096, 2048, 2048);
  }

  // 7) O = bf16(P0 + P1), into latb region
  pv_reduce<<<8192, 256, 0, stream>>>(P0a, P0b, P1w, Ob);

  // 8) out = O Wfc^T + bfc, unsplit (K=2048), f32 straight to d_out
  {
    GP P = {};
    P.A[0] = Ob; P.B[0] = wfb; P.C[0] = (char*)out;
    P.bias[0] = bfc; P.K[0] = 2048; P.flags[0] = 4;    // f32 out, bias col
    gemm8p<<<dim3(8, 16, 1), 512, 0, stream>>>(P, 2048, 2048, 2048);
  }
}

// Round 10
// 298.078 us; speedup vs baseline: 1.0626x; 1.0432x over previous
//
#include <hip/hip_runtime.h>
#include <hip/hip_bf16.h>
#include <math.h>

using bf16 = __hip_bfloat16;
typedef __attribute__((ext_vector_type(8))) __bf16 bf16x8;
typedef __attribute__((ext_vector_type(4))) float f32x4;

#define SBAR() asm volatile("s_barrier" ::: "memory")
#define WAITVM(n) asm volatile("s_waitcnt vmcnt(" #n ")" ::: "memory")
#define LGKM0() { asm volatile("s_waitcnt lgkmcnt(0)" ::: "memory"); __builtin_amdgcn_sched_barrier(0); }
// inline-asm ds_read_b128: invisible to compiler alias tracking (no auto drains)
#define DSR(dst, a, o) asm volatile("ds_read_b128 %0, %1 offset:" o : "=v"(dst) : "v"(a))

static __device__ __forceinline__ void gload16(const bf16* g, bf16* l) {
  __builtin_amdgcn_global_load_lds((const __attribute__((address_space(1))) void*)g,
                                   (__attribute__((address_space(3))) void*)l, 16, 0, 0);
}

struct GP {
  const bf16* A[6]; const bf16* B[6]; char* C[6];
  const float* bias[6];
  int K[6], flags[6], ktOff[6];   // flags: 1=causal-skip 2=bias-row 4=f32out 8=ktrunc
};
struct CvtP { const float* s[5]; bf16* d[5]; int n4[5]; };

// ---------------------------------------------------------------------------
// fused f32 -> bf16 conversion for 5 tensors
// ---------------------------------------------------------------------------
__global__ __launch_bounds__(256) void cvt_f32_bf16(CvtP p) {
  const int y = blockIdx.y;
  const int i = blockIdx.x * 256 + threadIdx.x;
  if (i >= p.n4[y]) return;
  const float4 v = reinterpret_cast<const float4*>(p.s[y])[i];
  union { bf16 h[4]; short4 s4; } u;
  u.h[0] = __float2bfloat16(v.x);
  u.h[1] = __float2bfloat16(v.y);
  u.h[2] = __float2bfloat16(v.z);
  u.h[3] = __float2bfloat16(v.w);
  *reinterpret_cast<short4*>(p.d[y] + 4 * (size_t)i) = u.s4;
}

// ---------------------------------------------------------------------------
// 8-phase NT GEMM, ONE barrier per phase (r7 engine = best measured) +
// XCD-aware bijective block swizzle (T1): consecutive logical blocks share
// A-row / B-col panels; mapping 8 consecutive logical blocks onto one XCD
// makes the shared panel an L2 hit instead of 8 XCD-local re-fetches.
// All grids used have (gx*gy) % 8 == 0 -> simple bijective form.
// Engine: BM=BN=256, BK=64, 512 thr / 8 waves (2M x 4N), per-wave 128x64.
// LDS: 2 dbuf x {A-k0, A-k1, B-k0, B-k1} halves (16KB each, 128KB).
// Phase: {asm ds_read 8|4 b128; stage 1 half (2 gload); [counted vmcnt];
// s_barrier; lgkmcnt(0)+sched_barrier; setprio(1); 16 MFMA; setprio(0)}.
// Swizzle: 16B slot = chunk ^ ((row>>1)&3) (measured 0 conflicts).
// ---------------------------------------------------------------------------
__global__ __launch_bounds__(512, 1) void gemm8p(GP P, int lda, int ldb, int ldc) {
  const int z = blockIdx.z;
  const int fl = P.flags[z];
  // XCD-aware bijective remap of (x,y) within this z-slice
  const int gx = (int)gridDim.x, gy = (int)gridDim.y;
  {
  }
  const int nwg = gx * gy;
  int wg = (int)blockIdx.y * gx + (int)blockIdx.x;
  wg = (wg & 7) * (nwg >> 3) + (wg >> 3);            // nwg % 8 == 0 for all grids
  const int bx = wg % gx;
  const int by0 = wg / gx;

  if ((fl & 1) && bx > by0) return;                  // causal block skip
  const int by = (fl & 8) ? (gy - 1 - by0) : by0;
  const int rowBase = by * 256;
  const int colBase = bx * 256;
  int kEnd = P.K[z];
  if (fl & 8) {
    const int lim = rowBase + 256 - P.ktOff[z];
    kEnd = kEnd < lim ? kEnd : lim;
    if (kEnd <= 0) return;                           // inert split-K block
  }
  const int NT = kEnd >> 6;                          // BK=64 tiles (>=4)

  const int tid  = threadIdx.x;
  const int lane = tid & 63;
  const int wid  = tid >> 6;
  const int wm = wid >> 2;          // 0..1 -> 128-row strip
  const int wn = wid & 3;           // 0..3 -> 64-col strip

  __shared__ alignas(16) bf16 ls[2][4][8192];  // [dbuf][A-k0,A-k1,B-k0,B-k1]

  f32x4 acc[8][4] = {};

  // staging: per half-tile 2 passes of 512thr x 16B; row = pass*128 + tid>>2
  const int r0  = tid >> 2;
  const int sw8 = ((tid & 3) ^ ((r0 >> 1) & 3)) * 8;    // pre-swizzled chunk
  const bf16* gA = P.A[z] + (size_t)(rowBase + r0) * lda + sw8;
  const bf16* gB = P.B[z] + (size_t)(colBase + r0) * ldb + sw8;

  // fragment read BYTE addresses (LDS): row*64B + swizzled-chunk*16B
  const uint lsbase = (uint)(size_t)(__attribute__((address_space(3))) void*)&ls[0][0][0];
  const int lr = lane >> 4, lc = lane & 15;
  uint aB[8], bB[4];
#pragma unroll
  for (int mi = 0; mi < 8; ++mi) {
    const int row = wm * 128 + mi * 16 + lc;
    aB[mi] = lsbase + (uint)(row * 64 + (lr ^ ((row >> 1) & 3)) * 16);
  }
#pragma unroll
  for (int ni = 0; ni < 4; ++ni) {
    const int row = wn * 64 + ni * 16 + lc;
    bB[ni] = lsbase + 32768u + (uint)(row * 64 + (lr ^ ((row >> 1) & 3)) * 16);
  }

  // stage half h of tile t: h 0=A-k0 1=A-k1 2=B-k0 3=B-k1
#define STG(t, h) { bf16* d = &ls[(t) & 1][h][0]; \
    if ((h) < 2) { const int ko = (t) * 64 + (h) * 32; \
      gload16(gA + ko, &d[tid * 8]); \
      gload16(gA + (size_t)128 * lda + ko, &d[4096 + tid * 8]); \
    } else { const int ko = (t) * 64 + ((h) - 2) * 32; \
      gload16(gB + ko, &d[tid * 8]); \
      gload16(gB + (size_t)128 * ldb + ko, &d[4096 + tid * 8]); } }

  // prologue: tile 0 fully staged, drain, publish
  STG(0, 0); STG(0, 2); STG(0, 1); STG(0, 3);
  WAITVM(0);
  SBAR();

  for (int t = 0; t < NT; ++t) {
    const uint dsel = (uint)(t & 1) << 16;
    uint ao[8], bo[4];
#pragma unroll
    for (int i = 0; i < 8; ++i) ao[i] = aB[i] + dsel;
#pragma unroll
    for (int i = 0; i < 4; ++i) bo[i] = bB[i] + dsel;
    const bool more = (t + 1 < NT);
    bf16x8 a0[4], a1[4], b0[4], b1[4];

    // ---- P1: read A-k0 (m0-3) + B-k0; stage A-k0(t+1)
#pragma unroll
    for (int i = 0; i < 4; ++i) DSR(a0[i], ao[i], "0");
#pragma unroll
    for (int i = 0; i < 4; ++i) DSR(b0[i], bo[i], "0");
    if (more) STG(t + 1, 0);
    SBAR();
    LGKM0();
    __builtin_amdgcn_s_setprio(1);
#pragma unroll
    for (int m = 0; m < 4; ++m)
#pragma unroll
      for (int n = 0; n < 4; ++n)
        acc[m][n] = __builtin_amdgcn_mfma_f32_16x16x32_bf16(a0[m], b0[n], acc[m][n], 0, 0, 0);
    __builtin_amdgcn_s_setprio(0);

    // ---- P2: read A-k0 (m4-7); stage B-k0(t+1); counted vmcnt
#pragma unroll
    for (int i = 0; i < 4; ++i) DSR(a1[i], ao[4 + i], "0");
    if (more) STG(t + 1, 2);
    if (t + 1 == NT) { WAITVM(0); } else { WAITVM(4); }  // A-k1,B-k1(t) landed
    SBAR();
    LGKM0();
    __builtin_amdgcn_s_setprio(1);
#pragma unroll
    for (int m = 0; m < 4; ++m)
#pragma unroll
      for (int n = 0; n < 4; ++n)
        acc[4 + m][n] = __builtin_amdgcn_mfma_f32_16x16x32_bf16(a1[m], b0[n], acc[4 + m][n], 0, 0, 0);
    __builtin_amdgcn_s_setprio(0);

    // ---- P3: read A-k1 (m0-3) + B-k1; stage A-k1(t+1)
#pragma unroll
    for (int i = 0; i < 4; ++i) DSR(a0[i], ao[i], "16384");
#pragma unroll
    for (int i = 0; i < 4; ++i) DSR(b1[i], bo[i], "16384");
    if (more) STG(t + 1, 1);
    SBAR();
    LGKM0();
    __builtin_amdgcn_s_setprio(1);
#pragma unroll
    for (int m = 0; m < 4; ++m)
#pragma unroll
      for (int n = 0; n < 4; ++n)
        acc[m][n] = __builtin_amdgcn_mfma_f32_16x16x32_bf16(a0[m], b1[n], acc[m][n], 0, 0, 0);
    __builtin_amdgcn_s_setprio(0);

    // ---- P4: read A-k1 (m4-7); stage B-k1(t+1); counted vmcnt
#pragma unroll
    for (int i = 0; i < 4; ++i) DSR(a1[i], ao[4 + i], "16384");
    if (more) STG(t + 1, 3);
    WAITVM(4);                       // A-k0,B-k0(t+1) landed (no-op last tile)
    SBAR();
    LGKM0();
    __builtin_amdgcn_s_setprio(1);
#pragma unroll
    for (int m = 0; m < 4; ++m)
#pragma unroll
      for (int n = 0; n < 4; ++n)
        acc[4 + m][n] = __builtin_amdgcn_mfma_f32_16x16x32_bf16(a1[m], b1[n], acc[4 + m][n], 0, 0, 0);
    __builtin_amdgcn_s_setprio(0);
  }
#undef STG

  const float* bias = P.bias[z];
  char* C = P.C[z];
#pragma unroll
  for (int m = 0; m < 8; ++m) {
    const int row0 = rowBase + wm * 128 + m * 16 + lr * 4;
#pragma unroll
    for (int n = 0; n < 4; ++n) {
      const int col = colBase + wn * 64 + n * 16 + lc;
      const float bcol = (bias && !(fl & 2)) ? bias[col] : 0.f;
#pragma unroll
      for (int j = 0; j < 4; ++j) {
        float v = acc[m][n][j] + bcol;
        if (fl & 2) v += bias[row0 + j];               // bias along rows (VT)
        const long idx = (long)(row0 + j) * ldc + col;
        if (fl & 4) reinterpret_cast<float*>(C)[idx] = v;
        else        reinterpret_cast<bf16*>(C)[idx] = __float2bfloat16(v);
      }
    }
  }
}

// ---------------------------------------------------------------------------
// RoPE on first 128 dims, in-place on bf16 [8192, 2048] (Q then K); pos=row%2048
// ---------------------------------------------------------------------------
__global__ __launch_bounds__(256) void rope_bf16(bf16* __restrict__ X) {
  const int idx = blockIdx.x * 256 + threadIdx.x;  // 8192*64 pairs
  const int row = idx >> 6;
  const int i   = idx & 63;
  const int t   = row & 2047;
  const float ang = (float)t * exp2f((float)i * -0.20762050593046f);
  float sn, cs;
  sincosf(ang, &sn, &cs);
  bf16* p = X + ((long)row << 11) + 2 * i;
  const float x1 = __bfloat162float(p[0]);
  const float x2 = __bfloat162float(p[1]);
  p[0] = __float2bfloat16(x1 * cs - x2 * sn);
  p[1] = __float2bfloat16(x2 * cs + x1 * sn);
}

// ---------------------------------------------------------------------------
// Causal row softmax over split-K partials; writes bf16 A row (stride 4096,
// zeros above diagonal), scale 1/sqrt(128), x2 factor.
// ---------------------------------------------------------------------------
__global__ __launch_bounds__(256) void softmax_causal(
    const float* __restrict__ S0, const float* __restrict__ S1,
    const float* __restrict__ S2, const float* __restrict__ S3,
    bf16* __restrict__ A0, bf16* __restrict__ A1) {
  const int t = blockIdx.x;
  const int b = blockIdx.y;
  const float* ra = (b ? S2 : S0) + (long)t * 2048;
  const float* rb = (b ? S3 : S1) + (long)t * 2048;
  bf16* orow = (b ? A1 : A0) + (long)t * 4096;
  const int L = t + 1;
  __shared__ float e[2048];
  __shared__ float red[4];
  const float scale = 0.0883883476483184f;  // 1/sqrt(128)
  const int lane = threadIdx.x & 63, wd = threadIdx.x >> 6;

  float mx = -INFINITY;
  for (int s = threadIdx.x; s < L; s += 256) {
    const float v = (ra[s] + rb[s]) * scale;
    e[s] = v;
    mx = fmaxf(mx, v);
  }
#pragma unroll
  for (int off = 1; off < 64; off <<= 1) mx = fmaxf(mx, __shfl_xor(mx, off));
  if (lane == 0) red[wd] = mx;
  __syncthreads();
  mx = fmaxf(fmaxf(red[0], red[1]), fmaxf(red[2], red[3]));
  __syncthreads();

  float sum = 0.f;
  for (int s = threadIdx.x; s < L; s += 256) {
    const float v = expf(e[s] - mx);
    e[s] = v;
    sum += v;
  }
#pragma unroll
  for (int off = 1; off < 64; off <<= 1) sum += __shfl_xor(sum, off);
  if (lane == 0) red[wd] = sum;
  __syncthreads();
  sum = red[0] + red[1] + red[2] + red[3];
  const float f = 2.f / sum;
  for (int s = threadIdx.x; s < 2048; s += 256) {
    const float v = (s < L) ? e[s] * f : 0.f;
    orow[s] = __float2bfloat16(v);
  }
}

// ---------------------------------------------------------------------------
// PV reduce: O = bf16(P0 + (row>=1024 ? P1 : 0));  P0 split per batch.
// ---------------------------------------------------------------------------
__global__ __launch_bounds__(256) void pv_reduce(
    const float* __restrict__ p0a, const float* __restrict__ p0b,
    const float* __restrict__ p1, bf16* __restrict__ O) {
  const long i4 = (long)blockIdx.x * 256 + threadIdx.x;  // [0, 2*2048*2048/4)
  const long g = i4 * 4;
  const int b = (int)(g >> 22);
  const long rem = g & ((1L << 22) - 1);
  const int r = (int)(rem >> 11);
  const float* p0 = b ? p0b : p0a;
  float4 v = *reinterpret_cast<const float4*>(p0 + rem);
  if (r >= 1024) {
    const float4 w = *reinterpret_cast<const float4*>(
        p1 + (long)b * (1024 * 2048) + (rem - (1L << 21)));
    v.x += w.x; v.y += w.y; v.z += w.z; v.w += w.w;
  }
  union { bf16 h[4]; short4 s; } u;
  u.h[0] = __float2bfloat16(v.x);
  u.h[1] = __float2bfloat16(v.y);
  u.h[2] = __float2bfloat16(v.z);
  u.h[3] = __float2bfloat16(v.w);
  *reinterpret_cast<short4*>(O + g) = u.s;
}

// ---------------------------------------------------------------------------
// FC reduce: out = Pf0 + Pf1 + bias[col]   (f32, [4096,2048])
// ---------------------------------------------------------------------------
__global__ __launch_bounds__(256) void fc_reduce(
    const float* __restrict__ pa, const float* __restrict__ pb,
    const float* __restrict__ bias, float* __restrict__ out) {
  const long i4 = (long)blockIdx.x * 256 + threadIdx.x;  // [0, 4096*2048/4)
  const long g = i4 * 4;
  const int col = (int)(g & 2047);
  const float4 a = reinterpret_cast<const float4*>(pa)[i4];
  const float4 b4 = reinterpret_cast<const float4*>(pb)[i4];
  const float4 bv = *reinterpret_cast<const float4*>(bias + col);
  float4 o;
  o.x = a.x + b4.x + bv.x;
  o.y = a.y + b4.y + bv.y;
  o.z = a.z + b4.z + bv.z;
  o.w = a.w + b4.w + bv.w;
  reinterpret_cast<float4*>(out)[i4] = o;
}

// ---------------------------------------------------------------------------
extern "C" void kernel_launch(void* const* d_in, const int* in_sizes, int n_in,
                              void* d_out, int out_size, void* d_ws, size_t ws_size,
                              hipStream_t stream) {
  (void)in_sizes; (void)n_in; (void)out_size; (void)ws_size;
  const float* lat = (const float*)d_in[0];
  const float* Wq  = (const float*)d_in[1];
  const float* bq  = (const float*)d_in[2];
  const float* Wk  = (const float*)d_in[3];
  const float* bk  = (const float*)d_in[4];
  const float* Wv  = (const float*)d_in[5];
  const float* bv  = (const float*)d_in[6];
  const float* Wfc = (const float*)d_in[7];
  const float* bfc = (const float*)d_in[8];
  float* out = (float*)d_out;

  constexpr long T = 2048, D = 2048, MT = 4096;    // B=2
  constexpr long TTB = T * T * 4;                  // 16.78 MB per f32 score buf
  char* w = (char*)d_ws;
  bf16* latb = (bf16*)w;  w += MT * D * 2;         // later overlaid by O
  bf16* wqb  = (bf16*)w;  w += D * D * 2;
  bf16* wkb  = (bf16*)w;  w += D * D * 2;
  bf16* wvb  = (bf16*)w;  w += D * D * 2;
  bf16* wfb  = (bf16*)w;  w += D * D * 2;
  bf16* Qb   = (bf16*)w;  w += MT * D * 2;         // Q,K contiguous (rope)
  bf16* Kb   = (bf16*)w;  w += MT * D * 2;
  bf16* VTb  = (bf16*)w;  w += MT * D * 2;
  float* S0  = (float*)w; w += TTB;                // b0 khalf0 partial
  float* S1  = (float*)w; w += TTB;                // b0 khalf1 partial
  float* P1w = (float*)w; w += TTB;                // PV khalf1 partial
  float* S2  = (float*)d_out;                      // b1 khalf0 (d_out lower)
  float* S3  = (float*)((char*)d_out + TTB);       // b1 khalf1 (d_out upper)
  bf16* A0   = (bf16*)S0;                          // A overlays (stride 4096)
  bf16* A1   = (bf16*)S3;
  float* P0a = S1;                                 // PV khalf0 partial, batch0
  float* P0b = S2;                                 // PV khalf0 partial, batch1
  bf16* Ob   = latb;                               // O overlays latb
  float* Pf0 = (float*)Qb;                         // FC khalf0 over Qb+Kb
  float* Pf1 = S0;                                 // FC khalf1 over S0+S1

  // 1) convert to bf16
  CvtP cp;
  cp.s[0] = lat; cp.d[0] = latb; cp.n4[0] = (int)(MT * D / 4);
  cp.s[1] = Wq;  cp.d[1] = wqb;  cp.n4[1] = (int)(D * D / 4);
  cp.s[2] = Wk;  cp.d[2] = wkb;  cp.n4[2] = (int)(D * D / 4);
  cp.s[3] = Wv;  cp.d[3] = wvb;  cp.n4[3] = (int)(D * D / 4);
  cp.s[4] = Wfc; cp.d[4] = wfb;  cp.n4[4] = (int)(D * D / 4);
  cvt_f32_bf16<<<dim3(8192, 5), 256, 0, stream>>>(cp);

  // 2) Q/K projections (+bias col)
  {
    GP P = {};
    P.A[0] = latb; P.B[0] = wqb; P.C[0] = (char*)Qb; P.bias[0] = bq; P.K[0] = 2048;
    P.A[1] = latb; P.B[1] = wkb; P.C[1] = (char*)Kb; P.bias[1] = bk; P.K[1] = 2048;
    gemm8p<<<dim3(8, 16, 2), 512, 0, stream>>>(P, 2048, 2048, 2048);
  }

  // 3) RoPE on Q and K (contiguous 8192 rows)
  rope_bf16<<<2048, 256, 0, stream>>>(Qb);

  // 4) VT-projection (z0,1: VT = Wv·lat^T + bv[row]) merged with causal
  //    split-K scores (z2..5)
  {
    GP P = {};
    for (int b = 0; b < 2; ++b) {
      P.A[b] = wvb; P.B[b] = latb + (long)b * T * D;
      P.C[b] = (char*)(VTb + (long)b * T * D);
      P.bias[b] = bv; P.K[b] = 2048; P.flags[b] = 2;   // bias-row, bf16 out
    }
    char* sc[4] = {(char*)S0, (char*)S1, (char*)S2, (char*)S3};
    for (int zz = 0; zz < 4; ++zz) {
      const int b = zz >> 1, kh = zz & 1;
      P.A[2 + zz] = Qb + (long)b * T * D + kh * 1024;
      P.B[2 + zz] = Kb + (long)b * T * D + kh * 1024;
      P.C[2 + zz] = sc[zz];
      P.K[2 + zz] = 1024; P.flags[2 + zz] = 1 | 4;     // causal, f32 out
    }
    gemm8p<<<dim3(8, 8, 6), 512, 0, stream>>>(P, 2048, 2048, 2048);
  }

  // 5) softmax rows (sum two k-half partials) -> bf16 A (stride 4096)
  softmax_causal<<<dim3(2048, 2), 256, 0, stream>>>(S0, S1, S2, S3, A0, A1);

  // 6) PV split-K: z = batch*2 + khalf; kEnd = min(1024, rowBase+256-kOff)
  {
    GP P = {};
    for (int z = 0; z < 4; ++z) {
      const int b = z >> 1, kh = z & 1;
      P.A[z] = (b ? A1 : A0) + kh * 1024;
      P.B[z] = VTb + (long)b * T * D + kh * 1024;
      P.C[z] = kh ? ((char*)P1w + (long)b * 1024 * 2048 * 4 - (long)1024 * 2048 * 4)
                  : (char*)(b ? P0b : P0a);
      P.K[z] = 1024; P.flags[z] = 8 | 4; P.ktOff[z] = kh * 1024;
    }
    gemm8p<<<dim3(8, 8, 4), 512, 0, stream>>>(P, 4096, 2048, 2048);
  }

  // 7) O = bf16(P0 + P1), into latb region
  pv_reduce<<<8192, 256, 0, stream>>>(P0a, P0b, P1w, Ob);

  // 8) FC split-K: 256 balanced blocks (vs 128 unsplit = half machine idle)
  {
    GP P = {};
    for (int kh = 0; kh < 2; ++kh) {
      P.A[kh] = Ob + kh * 1024;
      P.B[kh] = wfb + kh * 1024;
      P.C[kh] = (char*)(kh ? Pf1 : Pf0);
      P.K[kh] = 1024; P.flags[kh] = 4;
    }
    gemm8p<<<dim3(8, 16, 2), 512, 0, stream>>>(P, 2048, 2048, 2048);
  }

  // 9) out = Pf0 + Pf1 + bfc
  fc_reduce<<<8192, 256, 0, stream>>>(Pf0, Pf1, bfc, out);
}